// Round 1
// 137.957 us; speedup vs baseline: 1.0363x; 1.0363x over previous
//
#include <hip/hip_runtime.h>

// GnnLayer: out[50000,64] = leaky_relu((h[idx]/dist).reshape(N,2048) @ W + bias)
// v2 strategy: barrier-free f16 MFMA with direct-to-fragment global gathers.
//  - A-fragment (16x16x32): lane l needs h[idx[m=l&15][kn]][j0 + (l>>4)*8 .. +8]
//    -> one per-lane 16B global load, scaled by 1/dist via v_pk_mul_f16. No LDS.
//  - B pre-swizzled into fragment order by k_conv_w -> coalesced 16B/lane loads.
//  - K split across 4 waves (each wave: 64 nodes x K=512), LDS tree-reduce at end.
// ws layout: [0, 256KB) = W fragments f16; [256KB, +6.4MB) = h f16 [50000][64]

#define N_NODES 50000
#define KN      32
#define FIN     64
#define FOUT    64
#define MTILE   64

typedef __attribute__((ext_vector_type(4))) float    f32x4;
typedef __attribute__((ext_vector_type(8))) _Float16 f16x8;
typedef __attribute__((ext_vector_type(4))) _Float16 f16x4;

// h fp32 [N][64] -> f16. 800000 threads x 4 elems, coalesced both sides.
__global__ void k_conv_h(const float* __restrict__ src, _Float16* __restrict__ dst) {
    int i = blockIdx.x * blockDim.x + threadIdx.x;
    float4 v = ((const float4*)src)[i];
    f16x4 o = { (_Float16)v.x, (_Float16)v.y, (_Float16)v.z, (_Float16)v.w };
    ((f16x4*)dst)[i] = o;
}

// W[2048][64] fp32 -> f16 B-fragments in MFMA lane order:
//   wf[((kk*4 + t)*64 + lane)*8 + i] = W[kk*32 + (lane>>4)*8 + i][t*16 + (lane&15)]
// One block per kk (32 K-rows), LDS-tiled so reads and writes are coalesced.
__global__ void k_conv_w(const float* __restrict__ w, _Float16* __restrict__ wf) {
    __shared__ float s_w[32 * 64];  // W rows kk*32 .. +32
    const int kk = blockIdx.x, tid = threadIdx.x;
    for (int p = tid; p < 32 * 64; p += 256)
        s_w[p] = w[kk * 32 * 64 + p];
    __syncthreads();
    const int t = tid >> 6, lane = tid & 63;     // 4 tiles x 64 lanes = 256 threads
    const int lm = lane & 15, q = lane >> 4;
    f16x8 o;
    #pragma unroll
    for (int i = 0; i < 8; ++i)
        o[i] = (_Float16)s_w[(q * 8 + i) * 64 + t * 16 + lm];
    *(f16x8*)(wf + (((kk * 4 + t) * 64) + lane) * 8) = o;
}

__global__ __launch_bounds__(256, 3) void k_main(
        const _Float16* __restrict__ hf,    // f16 h [N][64]
        const float*    __restrict__ pos,   // [N][3]
        const int*      __restrict__ nidx,  // [N][32]
        const _Float16* __restrict__ wf,    // f16 W fragments
        const float*    __restrict__ bias,  // [64]
        float*          __restrict__ out)   // [N][64]
{
    __shared__ int2  s_e[KN * MTILE];     // [kn][m] {idx, scl bits}, 16 KB
    __shared__ float s_red[2 * 64 * 68];  // reduction scratch, 34 KB (stride 68: 16B-aligned rows, 2-way banks)

    const int tid = threadIdx.x;
    const int m0  = blockIdx.x * MTILE;

    // Phase 0: per-edge {neighbor idx, 1/dist}. m = p&63 so LDS writes are conflict-free.
    for (int p = tid; p < MTILE * KN; p += 256) {
        int m = p & 63, k = p >> 6;
        int node = m0 + m;
        int idx = 0; float scl = 0.f;
        if (node < N_NODES) {
            idx = nidx[node * KN + k];
            float dx = pos[node * 3 + 0] - pos[idx * 3 + 0];
            float dy = pos[node * 3 + 1] - pos[idx * 3 + 1];
            float dz = pos[node * 3 + 2] - pos[idx * 3 + 2];
            float sq = dx * dx + dy * dy + dz * dz;
            scl = (sq == 0.f) ? 2.0f : rsqrtf(sq);  // ref: dist=0.5 when sq==0
        }
        s_e[k * MTILE + m] = make_int2(idx, __float_as_int(scl));
    }
    __syncthreads();

    const int lane = tid & 63, wv = tid >> 6;
    const int lm = lane & 15, q = lane >> 4;

    // Wave wv handles K-slice kn in [wv*8, wv*8+8) for ALL 64 nodes (4 m-tiles).
    const _Float16* pb = wf + wv * 32768 + lane * 8;  // B frags for kk = wv*16 ..

    f32x4 acc[4][4] = {};  // [m-tile][n-tile]

    #pragma unroll 2
    for (int knl = 0; knl < 8; ++knl) {
        const int kb = (wv * 8 + knl) * MTILE + lm;
        const int2 e0 = s_e[kb];
        const int2 e1 = s_e[kb + 16];
        const int2 e2 = s_e[kb + 32];
        const int2 e3 = s_e[kb + 48];
        const _Float16* pa0 = hf + e0.x * FIN + q * 8;
        const _Float16* pa1 = hf + e1.x * FIN + q * 8;
        const _Float16* pa2 = hf + e2.x * FIN + q * 8;
        const _Float16* pa3 = hf + e3.x * FIN + q * 8;
        const _Float16 s0 = (_Float16)__int_as_float(e0.y);
        const _Float16 s1 = (_Float16)__int_as_float(e1.y);
        const _Float16 s2 = (_Float16)__int_as_float(e2.y);
        const _Float16 s3 = (_Float16)__int_as_float(e3.y);
        #pragma unroll
        for (int jh = 0; jh < 2; ++jh) {
            const int fo = ((knl * 2 + jh) * 4) * 512;  // B fragment elem offset for this kk
            f16x8 b0 = *(const f16x8*)(pb + fo);
            f16x8 b1 = *(const f16x8*)(pb + fo + 512);
            f16x8 b2 = *(const f16x8*)(pb + fo + 1024);
            f16x8 b3 = *(const f16x8*)(pb + fo + 1536);
            f16x8 a0 = *(const f16x8*)(pa0 + jh * 32) * s0;  // v_pk_mul_f16 x4
            f16x8 a1 = *(const f16x8*)(pa1 + jh * 32) * s1;
            f16x8 a2 = *(const f16x8*)(pa2 + jh * 32) * s2;
            f16x8 a3 = *(const f16x8*)(pa3 + jh * 32) * s3;
            acc[0][0] = __builtin_amdgcn_mfma_f32_16x16x32_f16(a0, b0, acc[0][0], 0, 0, 0);
            acc[0][1] = __builtin_amdgcn_mfma_f32_16x16x32_f16(a0, b1, acc[0][1], 0, 0, 0);
            acc[0][2] = __builtin_amdgcn_mfma_f32_16x16x32_f16(a0, b2, acc[0][2], 0, 0, 0);
            acc[0][3] = __builtin_amdgcn_mfma_f32_16x16x32_f16(a0, b3, acc[0][3], 0, 0, 0);
            acc[1][0] = __builtin_amdgcn_mfma_f32_16x16x32_f16(a1, b0, acc[1][0], 0, 0, 0);
            acc[1][1] = __builtin_amdgcn_mfma_f32_16x16x32_f16(a1, b1, acc[1][1], 0, 0, 0);
            acc[1][2] = __builtin_amdgcn_mfma_f32_16x16x32_f16(a1, b2, acc[1][2], 0, 0, 0);
            acc[1][3] = __builtin_amdgcn_mfma_f32_16x16x32_f16(a1, b3, acc[1][3], 0, 0, 0);
            acc[2][0] = __builtin_amdgcn_mfma_f32_16x16x32_f16(a2, b0, acc[2][0], 0, 0, 0);
            acc[2][1] = __builtin_amdgcn_mfma_f32_16x16x32_f16(a2, b1, acc[2][1], 0, 0, 0);
            acc[2][2] = __builtin_amdgcn_mfma_f32_16x16x32_f16(a2, b2, acc[2][2], 0, 0, 0);
            acc[2][3] = __builtin_amdgcn_mfma_f32_16x16x32_f16(a2, b3, acc[2][3], 0, 0, 0);
            acc[3][0] = __builtin_amdgcn_mfma_f32_16x16x32_f16(a3, b0, acc[3][0], 0, 0, 0);
            acc[3][1] = __builtin_amdgcn_mfma_f32_16x16x32_f16(a3, b1, acc[3][1], 0, 0, 0);
            acc[3][2] = __builtin_amdgcn_mfma_f32_16x16x32_f16(a3, b2, acc[3][2], 0, 0, 0);
            acc[3][3] = __builtin_amdgcn_mfma_f32_16x16x32_f16(a3, b3, acc[3][3], 0, 0, 0);
        }
    }

    // Cross-wave K-reduction: waves {0,1} write regions {0,1}; waves {2,3} add.
    // C/D layout: col = lane&15 (n), row = q*4 + r (m within tile).
    float* reg = s_red + (wv & 1) * (64 * 68);
    if (wv < 2) {
        #pragma unroll
        for (int mt = 0; mt < 4; ++mt)
            #pragma unroll
            for (int t = 0; t < 4; ++t)
                #pragma unroll
                for (int r = 0; r < 4; ++r)
                    reg[(mt * 16 + q * 4 + r) * 68 + t * 16 + lm] = acc[mt][t][r];
    }
    __syncthreads();
    if (wv >= 2) {
        #pragma unroll
        for (int mt = 0; mt < 4; ++mt)
            #pragma unroll
            for (int t = 0; t < 4; ++t)
                #pragma unroll
                for (int r = 0; r < 4; ++r)
                    reg[(mt * 16 + q * 4 + r) * 68 + t * 16 + lm] += acc[mt][t][r];
    }
    __syncthreads();

    // Epilogue: combine halves + bias + leaky_relu, coalesced f32x4 stores.
    const int row = tid >> 2, c0 = (tid & 3) * 16;
    const int node = m0 + row;
    if (node < N_NODES) {
        #pragma unroll
        for (int i = 0; i < 4; ++i) {
            int c = c0 + i * 4;
            f32x4 v0 = *(const f32x4*)(s_red + row * 68 + c);
            f32x4 v1 = *(const f32x4*)(s_red + 64 * 68 + row * 68 + c);
            f32x4 bb = *(const f32x4*)(bias + c);
            f32x4 o = v0 + v1 + bb;
            #pragma unroll
            for (int j = 0; j < 4; ++j) o[j] = o[j] > 0.f ? o[j] : 0.01f * o[j];
            *(f32x4*)(out + node * FOUT + c) = o;
        }
    }
}

extern "C" void kernel_launch(void* const* d_in, const int* in_sizes, int n_in,
                              void* d_out, int out_size, void* d_ws, size_t ws_size,
                              hipStream_t stream) {
    const float* h    = (const float*)d_in[0];
    const float* pos  = (const float*)d_in[1];
    const int*   nidx = (const int*)d_in[2];
    const float* w    = (const float*)d_in[3];
    const float* bias = (const float*)d_in[4];
    float* out = (float*)d_out;

    _Float16* wf = (_Float16*)d_ws;                      // 256 KB (fragment-ordered W)
    _Float16* hb = (_Float16*)((char*)d_ws + 262144);    // 6.4 MB (h in f16)

    k_conv_w<<<64, 256, 0, stream>>>(w, wf);
    k_conv_h<<<(N_NODES * FIN / 4) / 256, 256, 0, stream>>>(h, hb);
    k_main<<<(N_NODES + MTILE - 1) / MTILE, 256, 0, stream>>>(hb, pos, nidx, wf, bias, out);
}

// Round 2
// 136.054 us; speedup vs baseline: 1.0508x; 1.0140x over previous
//
#include <hip/hip_runtime.h>

// GnnLayer: out[50000,64] = leaky_relu((h[idx]/dist).reshape(N,2048) @ W + bias)
// v3: latency-bound fix -> 2x waves/CU. 512-thread blocks (8 waves), MTILE=64,
// hybrid split: wave = (mg in {0,1} : 32 nodes) x (kg in {0..3} : K=512).
// Barrier-free f16 MFMA main loop with direct-to-fragment global gathers and an
// explicit 1-deep A-prefetch pipeline. 2-stage cross-wave K-reduction in LDS.
// ws layout: [0, 256KB) = W fragments f16; [256KB, +6.4MB) = h f16 [50000][64]

#define N_NODES 50000
#define KN      32
#define FIN     64
#define FOUT    64
#define MTILE   64

typedef __attribute__((ext_vector_type(4))) float    f32x4;
typedef __attribute__((ext_vector_type(8))) _Float16 f16x8;
typedef __attribute__((ext_vector_type(4))) _Float16 f16x4;

// Merged prep: blocks [0,64) convert W -> fragment-ordered f16; blocks [64,..)
// convert h fp32 -> f16 (coalesced float4 -> f16x4).
__global__ void k_prep(const float* __restrict__ w, _Float16* __restrict__ wf,
                       const float* __restrict__ h, _Float16* __restrict__ hb) {
    __shared__ float s_w[32 * 64];
    const int tid = threadIdx.x;
    if (blockIdx.x < 64) {
        // W[2048][64] fp32 -> f16 B-fragments in MFMA lane order:
        //   wf[kk*2048 + t*512 + lane*8 + i] = W[kk*32 + (lane>>4)*8 + i][t*16 + (lane&15)]
        const int kk = blockIdx.x;
        for (int p = tid; p < 32 * 64; p += 256)
            s_w[p] = w[kk * 32 * 64 + p];
        __syncthreads();
        const int t = tid >> 6, lane = tid & 63;
        const int lm = lane & 15, q = lane >> 4;
        f16x8 o;
        #pragma unroll
        for (int i = 0; i < 8; ++i)
            o[i] = (_Float16)s_w[(q * 8 + i) * 64 + t * 16 + lm];
        *(f16x8*)(wf + kk * 2048 + t * 512 + lane * 8) = o;
    } else {
        const int i = (blockIdx.x - 64) * 256 + tid;  // 800000 float4s
        float4 v = ((const float4*)h)[i];
        f16x4 o = { (_Float16)v.x, (_Float16)v.y, (_Float16)v.z, (_Float16)v.w };
        ((f16x4*)hb)[i] = o;
    }
}

__global__ __launch_bounds__(512, 6) void k_main(
        const _Float16* __restrict__ hf,    // f16 h [N][64]
        const float*    __restrict__ pos,   // [N][3]
        const int*      __restrict__ nidx,  // [N][32]
        const _Float16* __restrict__ wf,    // f16 W fragments
        const float*    __restrict__ bias,  // [64]
        float*          __restrict__ out)   // [N][64]
{
    __shared__ int2  s_e[KN * MTILE];     // [kn][m] {idx, scl bits}, 16 KB
    __shared__ float s_red[2 * 64 * 68];  // 2 reduction regions, 34 KB

    const int tid = threadIdx.x;
    const int m0  = blockIdx.x * MTILE;

    // Phase 0: per-edge {neighbor idx, 1/dist}. m = p&63 -> conflict-free writes.
    for (int p = tid; p < MTILE * KN; p += 512) {
        int m = p & 63, k = p >> 6;
        int node = m0 + m;
        int idx = 0; float scl = 0.f;
        if (node < N_NODES) {
            idx = nidx[node * KN + k];
            float dx = pos[node * 3 + 0] - pos[idx * 3 + 0];
            float dy = pos[node * 3 + 1] - pos[idx * 3 + 1];
            float dz = pos[node * 3 + 2] - pos[idx * 3 + 2];
            float sq = dx * dx + dy * dy + dz * dz;
            scl = (sq == 0.f) ? 2.0f : rsqrtf(sq);  // ref: dist=0.5 when sq==0
        }
        s_e[k * MTILE + m] = make_int2(idx, __float_as_int(scl));
    }
    __syncthreads();

    const int lane = tid & 63, wv = tid >> 6;
    const int lm = lane & 15, q = lane >> 4;
    const int mg = wv & 1;    // m-group: nodes mg*32 .. +32 (m-tiles 2mg, 2mg+1)
    const int kg = wv >> 1;   // k-group: kn in [kg*8, kg*8+8)

    const _Float16* pb = wf + lane * 8;
    const int ebase = (kg * 8) * MTILE + mg * 32 + lm;

    f32x4 acc[2][4] = {};  // [m-tile][n-tile]

    // Prologue: gather A-fragments for knl=0 (unscaled).
    int2 e0 = s_e[ebase], e1 = s_e[ebase + 16];
    const _Float16* pa0 = hf + e0.x * FIN + q * 8;
    const _Float16* pa1 = hf + e1.x * FIN + q * 8;
    f16x8 A00 = *(const f16x8*)pa0, A01 = *(const f16x8*)(pa0 + 32);
    f16x8 A10 = *(const f16x8*)pa1, A11 = *(const f16x8*)(pa1 + 32);
    _Float16 s0 = (_Float16)__int_as_float(e0.y);
    _Float16 s1 = (_Float16)__int_as_float(e1.y);

    #pragma unroll
    for (int knl = 0; knl < 8; ++knl) {
        // Prefetch next iteration's gathers before this iteration's MFMAs.
        f16x8 N00, N01, N10, N11;
        _Float16 ns0, ns1;
        if (knl < 7) {
            int eb = ebase + (knl + 1) * MTILE;
            int2 f0 = s_e[eb], f1 = s_e[eb + 16];
            const _Float16* q0 = hf + f0.x * FIN + q * 8;
            const _Float16* q1 = hf + f1.x * FIN + q * 8;
            N00 = *(const f16x8*)q0; N01 = *(const f16x8*)(q0 + 32);
            N10 = *(const f16x8*)q1; N11 = *(const f16x8*)(q1 + 32);
            ns0 = (_Float16)__int_as_float(f0.y);
            ns1 = (_Float16)__int_as_float(f1.y);
        }

        const _Float16* pbb = pb + ((kg * 8 + knl) * 2) * 2048;
        {   // jh = 0 (features 0..31 of this neighbor)
            f16x8 a0 = A00 * s0, a1 = A10 * s1;
            f16x8 b0 = *(const f16x8*)(pbb);
            f16x8 b1 = *(const f16x8*)(pbb + 512);
            f16x8 b2 = *(const f16x8*)(pbb + 1024);
            f16x8 b3 = *(const f16x8*)(pbb + 1536);
            acc[0][0] = __builtin_amdgcn_mfma_f32_16x16x32_f16(a0, b0, acc[0][0], 0, 0, 0);
            acc[0][1] = __builtin_amdgcn_mfma_f32_16x16x32_f16(a0, b1, acc[0][1], 0, 0, 0);
            acc[0][2] = __builtin_amdgcn_mfma_f32_16x16x32_f16(a0, b2, acc[0][2], 0, 0, 0);
            acc[0][3] = __builtin_amdgcn_mfma_f32_16x16x32_f16(a0, b3, acc[0][3], 0, 0, 0);
            acc[1][0] = __builtin_amdgcn_mfma_f32_16x16x32_f16(a1, b0, acc[1][0], 0, 0, 0);
            acc[1][1] = __builtin_amdgcn_mfma_f32_16x16x32_f16(a1, b1, acc[1][1], 0, 0, 0);
            acc[1][2] = __builtin_amdgcn_mfma_f32_16x16x32_f16(a1, b2, acc[1][2], 0, 0, 0);
            acc[1][3] = __builtin_amdgcn_mfma_f32_16x16x32_f16(a1, b3, acc[1][3], 0, 0, 0);
        }
        {   // jh = 1 (features 32..63)
            f16x8 a0 = A01 * s0, a1 = A11 * s1;
            f16x8 b0 = *(const f16x8*)(pbb + 2048);
            f16x8 b1 = *(const f16x8*)(pbb + 2560);
            f16x8 b2 = *(const f16x8*)(pbb + 3072);
            f16x8 b3 = *(const f16x8*)(pbb + 3584);
            acc[0][0] = __builtin_amdgcn_mfma_f32_16x16x32_f16(a0, b0, acc[0][0], 0, 0, 0);
            acc[0][1] = __builtin_amdgcn_mfma_f32_16x16x32_f16(a0, b1, acc[0][1], 0, 0, 0);
            acc[0][2] = __builtin_amdgcn_mfma_f32_16x16x32_f16(a0, b2, acc[0][2], 0, 0, 0);
            acc[0][3] = __builtin_amdgcn_mfma_f32_16x16x32_f16(a0, b3, acc[0][3], 0, 0, 0);
            acc[1][0] = __builtin_amdgcn_mfma_f32_16x16x32_f16(a1, b0, acc[1][0], 0, 0, 0);
            acc[1][1] = __builtin_amdgcn_mfma_f32_16x16x32_f16(a1, b1, acc[1][1], 0, 0, 0);
            acc[1][2] = __builtin_amdgcn_mfma_f32_16x16x32_f16(a1, b2, acc[1][2], 0, 0, 0);
            acc[1][3] = __builtin_amdgcn_mfma_f32_16x16x32_f16(a1, b3, acc[1][3], 0, 0, 0);
        }
        if (knl < 7) {
            A00 = N00; A01 = N01; A10 = N10; A11 = N11;
            s0 = ns0; s1 = ns1;
        }
    }

    // Cross-wave K-reduction: kg{0,1} write region kg; kg{2,3} add into region kg-2.
    // C/D layout: col = lane&15 (n), row = q*4 + r. Global row = mg*32 + mt*16 + row.
    float* reg = s_red + (kg & 1) * (64 * 68);
    if (kg < 2) {
        #pragma unroll
        for (int mt = 0; mt < 2; ++mt)
            #pragma unroll
            for (int t = 0; t < 4; ++t)
                #pragma unroll
                for (int r = 0; r < 4; ++r)
                    reg[(mg * 32 + mt * 16 + q * 4 + r) * 68 + t * 16 + lm] = acc[mt][t][r];
    }
    __syncthreads();
    if (kg >= 2) {
        #pragma unroll
        for (int mt = 0; mt < 2; ++mt)
            #pragma unroll
            for (int t = 0; t < 4; ++t)
                #pragma unroll
                for (int r = 0; r < 4; ++r)
                    reg[(mg * 32 + mt * 16 + q * 4 + r) * 68 + t * 16 + lm] += acc[mt][t][r];
    }
    __syncthreads();

    // Epilogue: region0 + region1 + bias, leaky_relu, coalesced f32x4 stores.
    const int row = tid >> 3, c0 = (tid & 7) * 8;
    const int node = m0 + row;
    if (node < N_NODES) {
        #pragma unroll
        for (int i = 0; i < 2; ++i) {
            int c = c0 + i * 4;
            f32x4 v0 = *(const f32x4*)(s_red + row * 68 + c);
            f32x4 v1 = *(const f32x4*)(s_red + 64 * 68 + row * 68 + c);
            f32x4 bb = *(const f32x4*)(bias + c);
            f32x4 o = v0 + v1 + bb;
            #pragma unroll
            for (int j = 0; j < 4; ++j) o[j] = o[j] > 0.f ? o[j] : 0.01f * o[j];
            *(f32x4*)(out + node * FOUT + c) = o;
        }
    }
}

extern "C" void kernel_launch(void* const* d_in, const int* in_sizes, int n_in,
                              void* d_out, int out_size, void* d_ws, size_t ws_size,
                              hipStream_t stream) {
    const float* h    = (const float*)d_in[0];
    const float* pos  = (const float*)d_in[1];
    const int*   nidx = (const int*)d_in[2];
    const float* w    = (const float*)d_in[3];
    const float* bias = (const float*)d_in[4];
    float* out = (float*)d_out;

    _Float16* wf = (_Float16*)d_ws;                      // 256 KB (fragment-ordered W)
    _Float16* hb = (_Float16*)((char*)d_ws + 262144);    // 6.4 MB (h in f16)

    k_prep<<<64 + (N_NODES * FIN / 4) / 256, 256, 0, stream>>>(w, wf, h, hb);
    k_main<<<(N_NODES + MTILE - 1) / MTILE, 512, 0, stream>>>(hb, pos, nidx, wf, bias, out);
}